// Round 6
// baseline (558.612 us; speedup 1.0000x reference)
//
#include <hip/hip_runtime.h>

// topk cross-entropy: N=262144 rows, C=128 classes, K = int(0.7*N) = 183500.
// Round 6: (a) loss grid 512->2048 (was 16% occupancy, latency-bound at
// 485 GB/s); (b) fold the sum pass into the refine pass via hierarchical
// per-bin sums (S1 direct + S2 bin sums + S3 exact count*value), so only
// 3 graph nodes: memset -> loss+scan1 -> refine+scan2/3+finalize.
// Exact 12/10/10-bit radix select on float bits (losses >= 0 => monotone);
// tie-exact mean = (S1 + S2 + S3 + (K - cnt_gt)*thr) / K.

#define NCLASS 128
#define NREP 8
#define TPB 256
#define LOSS_GRID 2048
#define REF_GRID 256

struct Scalars {
  unsigned sel1;
  unsigned cnt_above;   // count strictly above sel1 bin (after pass 1)
  int krem;             // remaining rank within sel1 bin
};

__device__ __forceinline__ unsigned aload_u(const unsigned* p) {
  return __hip_atomic_load(p, __ATOMIC_RELAXED, __HIP_MEMORY_SCOPE_AGENT);
}
__device__ __forceinline__ float aload_f(const float* p) {
  return __hip_atomic_load(p, __ATOMIC_RELAXED, __HIP_MEMORY_SCOPE_AGENT);
}
__device__ __forceinline__ double aload_d(const double* p) {
  return __hip_atomic_load(p, __ATOMIC_RELAXED, __HIP_MEMORY_SCOPE_AGENT);
}

__device__ __forceinline__ unsigned suffix_incl_u(unsigned x, int lane) {
#pragma unroll
  for (int off = 1; off < 64; off <<= 1) {
    unsigned v = __shfl_down(x, off, 64);
    if (lane + off < 64) x += v;
  }
  return x;
}

__device__ __forceinline__ double xor_reduce_d(double x) {
#pragma unroll
  for (int off = 32; off > 0; off >>= 1) x += __shfl_xor(x, off, 64);
  return x;
}

// Last-block-done ticket (round-5-verified pattern).
__device__ __forceinline__ bool block_is_last(unsigned* ticket, unsigned nblocks) {
  __shared__ int amLast;
  __threadfence();
  __syncthreads();
  if (threadIdx.x == 0)
    amLast = (__hip_atomic_fetch_add(ticket, 1u, __ATOMIC_ACQ_REL,
                                     __HIP_MEMORY_SCOPE_AGENT) == nblocks - 1)
                 ? 1 : 0;
  __syncthreads();
  return amLast != 0;
}

// Descending-rank select on a histogram (nrep replicas summed), lanes 0..63.
// Outputs valid on all 64 lanes.
__device__ __forceinline__ void scan_desc(const unsigned* hist, int nbins,
                                          int nrep, unsigned Ktar,
                                          int* bin_out, unsigned* above_out) {
  const int lane = threadIdx.x;       // caller guarantees < 64
  const int bpt = nbins >> 6;
  unsigned csum = 0;
  for (int rr = 0; rr < nrep; ++rr) {
    const unsigned* hp = hist + (size_t)rr * nbins + lane * bpt;
    for (int i = 0; i < bpt; ++i) csum += aload_u(hp + i);
  }
  unsigned suf = suffix_incl_u(csum, lane);
  unsigned long long mask = __ballot(suf >= Ktar);
  int c = 63 - __builtin_clzll(mask);
  unsigned aboveC = __shfl(suf - csum, c, 64);   // strictly above chunk c

  unsigned h = 0;
  if (lane < bpt)
    for (int rr = 0; rr < nrep; ++rr)
      h += aload_u(hist + (size_t)rr * nbins + c * bpt + lane);
  unsigned suf2 = suffix_incl_u(h, lane);
  unsigned long long mask2 = __ballot((lane < bpt) && (aboveC + suf2 >= Ktar));
  int u = 63 - __builtin_clzll(mask2);
  unsigned above = aboveC + __shfl(suf2 - h, u, 64); // strictly above bin
  *bin_out = c * bpt + u;
  *above_out = above;
}

// ---- dispatch 2: losses + 12-bit histogram; last block does scan level 1 ----
__global__ __launch_bounds__(TPB) void loss_hist_kernel(
    const float* __restrict__ x, const int* __restrict__ tgt,
    float* __restrict__ losses, unsigned* __restrict__ hist1,
    Scalars* __restrict__ sc, unsigned* __restrict__ tickets, int N, int K) {
  __shared__ unsigned lh[4096];
  for (int i = threadIdx.x; i < 4096; i += TPB) lh[i] = 0;
  __syncthreads();

  const int lane = threadIdx.x & 63;
  const int j = lane & 7;        // float4 column within row
  const int r = lane >> 3;       // row within the wave's 8-row group
  const int gw = blockIdx.x * (TPB / 64) + (threadIdx.x >> 6);
  const int W = LOSS_GRID * (TPB / 64);
  for (int base = gw; base * 8 < N; base += W) {
    const int row = base * 8 + r;
    const float4* rp = (const float4*)(x + (size_t)row * NCLASS);
    float4 a = rp[j];
    float4 b = rp[j + 8];
    float4 c = rp[j + 16];
    float4 d = rp[j + 24];
    float xt = 0.0f;
    if (j == 0) {                      // only 8 lanes gather target logit
      int t = tgt[row];
      xt = x[(size_t)row * NCLASS + t];
    }

    float m = fmaxf(fmaxf(fmaxf(a.x, a.y), fmaxf(a.z, a.w)),
                    fmaxf(fmaxf(b.x, b.y), fmaxf(b.z, b.w)));
    m = fmaxf(m, fmaxf(fmaxf(c.x, c.y), fmaxf(c.z, c.w)));
    m = fmaxf(m, fmaxf(fmaxf(d.x, d.y), fmaxf(d.z, d.w)));
    m = fmaxf(m, __shfl_xor(m, 1, 64));
    m = fmaxf(m, __shfl_xor(m, 2, 64));
    m = fmaxf(m, __shfl_xor(m, 4, 64));

    float s = __expf(a.x - m) + __expf(a.y - m) + __expf(a.z - m) + __expf(a.w - m)
            + __expf(b.x - m) + __expf(b.y - m) + __expf(b.z - m) + __expf(b.w - m)
            + __expf(c.x - m) + __expf(c.y - m) + __expf(c.z - m) + __expf(c.w - m)
            + __expf(d.x - m) + __expf(d.y - m) + __expf(d.z - m) + __expf(d.w - m);
    s += __shfl_xor(s, 1, 64);
    s += __shfl_xor(s, 2, 64);
    s += __shfl_xor(s, 4, 64);

    if (j == 0) {
      float loss = fmaxf(__logf(s) + m - xt, 0.0f);
      losses[row] = loss;
      atomicAdd(&lh[__float_as_uint(loss) >> 20], 1u);
    }
  }
  __syncthreads();
  unsigned* h = hist1 + (size_t)(blockIdx.x & (NREP - 1)) * 4096;
  for (int i = threadIdx.x; i < 4096; i += TPB) {
    unsigned v = lh[i];
    if (v) atomicAdd(&h[i], v);
  }

  if (block_is_last(&tickets[0], LOSS_GRID) && threadIdx.x < 64) {
    int bin; unsigned above;
    scan_desc(hist1, 4096, NREP, (unsigned)K, &bin, &above);
    if (threadIdx.x == 0) {
      sc->sel1 = (unsigned)bin;
      sc->cnt_above = above;
      sc->krem = K - (int)above;
    }
  }
}

// ---- dispatch 3: 20-bit refine + hierarchical sums; last block finalizes ----
__global__ __launch_bounds__(TPB) void refine_final_kernel(
    const float* __restrict__ losses, unsigned* __restrict__ hist2,
    float* __restrict__ hsum2, unsigned* __restrict__ fine,
    Scalars* __restrict__ sc, unsigned* __restrict__ tickets,
    double* __restrict__ partials, float* __restrict__ out, int N, int K) {
  __shared__ unsigned lc[1024];
  __shared__ float lsum[1024];
  __shared__ double dsm[TPB / 64];
  __shared__ double S1sh;
  for (int i = threadIdx.x; i < 1024; i += TPB) { lc[i] = 0; lsum[i] = 0.0f; }
  __syncthreads();

  const int lane = threadIdx.x & 63;
  const unsigned sel1 = sc->sel1;
  const float4* L4 = (const float4*)losses;
  const int n4 = N >> 2;
  double accS1 = 0.0;   // sum of elements in coarse bins strictly above sel1
  for (int idx = blockIdx.x * TPB + threadIdx.x; idx < n4;
       idx += REF_GRID * TPB) {
    float4 v = L4[idx];
#pragma unroll
    for (int comp = 0; comp < 4; ++comp) {
      float f = (comp == 0) ? v.x : (comp == 1) ? v.y : (comp == 2) ? v.z : v.w;
      unsigned b = __float_as_uint(f);
      unsigned hi = b >> 20;
      if (hi > sel1) {
        accS1 += (double)f;
      } else if (hi == sel1) {
        atomicAdd(&lc[(b >> 10) & 1023u], 1u);
        atomicAdd(&lsum[(b >> 10) & 1023u], f);
        atomicAdd(&fine[b & 0xFFFFFu], 1u);
      }
    }
  }
  // block-reduce S1 partial
  accS1 = xor_reduce_d(accS1);
  if (lane == 0) dsm[threadIdx.x >> 6] = accS1;
  __syncthreads();
  if (threadIdx.x == 0)
    partials[blockIdx.x] = dsm[0] + dsm[1] + dsm[2] + dsm[3];
  // flush level-2 count + sum
  unsigned* h = hist2 + (size_t)(blockIdx.x & (NREP - 1)) * 1024;
  for (int i = threadIdx.x; i < 1024; i += TPB) {
    unsigned c = lc[i];
    if (c) { atomicAdd(&h[i], c); atomicAdd(&hsum2[i], lsum[i]); }
  }

  if (block_is_last(&tickets[1], REF_GRID)) {
    // S1 total (256 partials, one per thread)
    double s1 = aload_d(&partials[threadIdx.x]);
    s1 = xor_reduce_d(s1);
    if (lane == 0) dsm[threadIdx.x >> 6] = s1;
    __syncthreads();
    if (threadIdx.x == 0) S1sh = dsm[0] + dsm[1] + dsm[2] + dsm[3];
    __syncthreads();

    if (threadIdx.x < 64) {
      const unsigned krem = (unsigned)sc->krem;
      int sel2; unsigned above2;
      scan_desc(hist2, 1024, NREP, krem, &sel2, &above2);
      const unsigned krem2 = krem - above2;

      // S2: sums of 10-bit bins strictly above sel2 (within sel1 bin)
      double s2 = 0.0;
      for (int b = sel2 + 1 + lane; b < 1024; b += 64)
        s2 += (double)aload_f(&hsum2[b]);
      s2 = xor_reduce_d(s2);

      // scan level 3 on fine counts within sel2's region
      const unsigned* freg = fine + ((size_t)sel2 << 10);
      int bin3; unsigned above3;
      scan_desc(freg, 1024, 1, krem2, &bin3, &above3);

      // S3: exact — all elements in a fine bin share the same 32-bit value
      const unsigned pfx = (sel1 << 20) | ((unsigned)sel2 << 10);
      double s3 = 0.0;
      for (int t = bin3 + 1 + lane; t < 1024; t += 64) {
        unsigned c = aload_u(&freg[t]);
        if (c) s3 += (double)c * (double)__uint_as_float(pfx | (unsigned)t);
      }
      s3 = xor_reduce_d(s3);

      if (lane == 0) {
        unsigned thr_bits = pfx | (unsigned)bin3;
        unsigned cnt_gt = sc->cnt_above + above2 + above3;
        double thrv = (double)__uint_as_float(thr_bits);
        double mean = (S1sh + s2 + s3 +
                       (double)(K - (int)cnt_gt) * thrv) / (double)K;
        *out = (float)mean;
      }
    }
  }
}

extern "C" void kernel_launch(void* const* d_in, const int* in_sizes, int n_in,
                              void* d_out, int out_size, void* d_ws, size_t ws_size,
                              hipStream_t stream) {
  const float* x = (const float*)d_in[0];
  const int* tgt = (const int*)d_in[1];
  float* out = (float*)d_out;
  int N = in_sizes[1];                 // 262144 rows
  int K = (int)(0.7 * (double)N);      // 183500, matches Python int()

  char* ws = (char*)d_ws;
  const size_t OFF_H1 = (size_t)N * 4;                       // losses: 1 MiB
  const size_t OFF_H2 = OFF_H1 + (size_t)NREP * 4096 * 4;    // hist1: 128 KiB
  const size_t OFF_HS = OFF_H2 + (size_t)NREP * 1024 * 4;    // hist2: 32 KiB
  const size_t OFF_SC = OFF_HS + 1024 * 4;                   // hsum2: 4 KiB
  const size_t OFF_TK = OFF_SC + 128;                        // scalars
  const size_t OFF_FN = OFF_TK + 128;                        // tickets
  const size_t OFF_PT = OFF_FN + (size_t)(1u << 20) * 4;     // fine: 4 MiB
  // partials: REF_GRID doubles after OFF_PT (written before read; no zeroing)

  float* losses = (float*)ws;
  unsigned* hist1 = (unsigned*)(ws + OFF_H1);
  unsigned* hist2 = (unsigned*)(ws + OFF_H2);
  float* hsum2 = (float*)(ws + OFF_HS);
  Scalars* sc = (Scalars*)(ws + OFF_SC);
  unsigned* tickets = (unsigned*)(ws + OFF_TK);
  unsigned* fine = (unsigned*)(ws + OFF_FN);
  double* partials = (double*)(ws + OFF_PT);

  // zero hist1 + hist2 + hsum2 + scalars + tickets + fine in one fill (~4.4 MB)
  hipMemsetAsync(ws + OFF_H1, 0, OFF_PT - OFF_H1, stream);

  loss_hist_kernel<<<LOSS_GRID, TPB, 0, stream>>>(x, tgt, losses, hist1, sc,
                                                  tickets, N, K);
  refine_final_kernel<<<REF_GRID, TPB, 0, stream>>>(losses, hist2, hsum2, fine,
                                                    sc, tickets, partials, out,
                                                    N, K);
}

// Round 7
// 214.092 us; speedup vs baseline: 2.6092x; 2.6092x over previous
//
#include <hip/hip_runtime.h>

// topk cross-entropy: N=262144 rows, C=128 classes, K = int(0.7*N) = 183500.
// Round 7: NO device-scope fences (R4/R5/R6 showed __threadfence costs
// ~O(us)/block on CDNA4, scaling with block count). Kernel-boundary sync only:
//   memset -> loss+hist12 -> scan1(1 blk) -> refine+sums -> finalize(1 blk).
// Exact 12/10/10-bit radix select on float bits (losses >= 0 => monotone);
// tie-exact mean = (S1 + S2 + S3 + (K - cnt_gt)*thr) / K.

#define NCLASS 128
#define NREP 8
#define TPB 256
#define LOSS_GRID 2048
#define REF_GRID 256

struct Scalars {
  unsigned sel1;
  unsigned cnt_above;   // count strictly above sel1 bin (after pass 1)
  int krem;             // remaining rank within sel1 bin
};

__device__ __forceinline__ unsigned suffix_incl_u(unsigned x, int lane) {
#pragma unroll
  for (int off = 1; off < 64; off <<= 1) {
    unsigned v = __shfl_down(x, off, 64);
    if (lane + off < 64) x += v;
  }
  return x;
}

__device__ __forceinline__ double xor_reduce_d(double x) {
#pragma unroll
  for (int off = 32; off > 0; off >>= 1) x += __shfl_xor(x, off, 64);
  return x;
}

// Descending-rank select on a histogram (nrep replicas summed). Must be called
// by threads 0..63 of one wave. Outputs valid on all 64 lanes.
__device__ __forceinline__ void scan_desc(const unsigned* __restrict__ hist,
                                          int nbins, int nrep, unsigned Ktar,
                                          int* bin_out, unsigned* above_out) {
  const int lane = threadIdx.x;
  const int bpt = nbins >> 6;
  unsigned csum = 0;
  for (int rr = 0; rr < nrep; ++rr) {
    const unsigned* hp = hist + (size_t)rr * nbins + lane * bpt;
    for (int i = 0; i < bpt; ++i) csum += hp[i];
  }
  unsigned suf = suffix_incl_u(csum, lane);
  unsigned long long mask = __ballot(suf >= Ktar);
  int c = 63 - __builtin_clzll(mask);
  unsigned aboveC = __shfl(suf - csum, c, 64);   // strictly above chunk c

  unsigned h = 0;
  if (lane < bpt)
    for (int rr = 0; rr < nrep; ++rr)
      h += hist[(size_t)rr * nbins + c * bpt + lane];
  unsigned suf2 = suffix_incl_u(h, lane);
  unsigned long long mask2 = __ballot((lane < bpt) && (aboveC + suf2 >= Ktar));
  int u = 63 - __builtin_clzll(mask2);
  unsigned above = aboveC + __shfl(suf2 - h, u, 64); // strictly above bin
  *bin_out = c * bpt + u;
  *above_out = above;
}

// ---- node 2: losses + 12-bit histogram (no fence, no ticket) ----
__global__ __launch_bounds__(TPB) void loss_hist_kernel(
    const float* __restrict__ x, const int* __restrict__ tgt,
    float* __restrict__ losses, unsigned* __restrict__ hist1, int N) {
  __shared__ unsigned lh[4096];
  for (int i = threadIdx.x; i < 4096; i += TPB) lh[i] = 0;
  __syncthreads();

  const int lane = threadIdx.x & 63;
  const int j = lane & 7;        // float4 column within row
  const int r = lane >> 3;       // row within the wave's 8-row group
  const int gw = blockIdx.x * (TPB / 64) + (threadIdx.x >> 6);
  const int W = LOSS_GRID * (TPB / 64);
  for (int base = gw; base * 8 < N; base += W) {
    const int row = base * 8 + r;
    const float4* rp = (const float4*)(x + (size_t)row * NCLASS);
    float4 a = rp[j];
    float4 b = rp[j + 8];
    float4 c = rp[j + 16];
    float4 d = rp[j + 24];
    float xt = 0.0f;
    if (j == 0) {                      // 8 lanes gather the target logit
      int t = tgt[row];
      xt = x[(size_t)row * NCLASS + t];
    }

    float m = fmaxf(fmaxf(fmaxf(a.x, a.y), fmaxf(a.z, a.w)),
                    fmaxf(fmaxf(b.x, b.y), fmaxf(b.z, b.w)));
    m = fmaxf(m, fmaxf(fmaxf(c.x, c.y), fmaxf(c.z, c.w)));
    m = fmaxf(m, fmaxf(fmaxf(d.x, d.y), fmaxf(d.z, d.w)));
    m = fmaxf(m, __shfl_xor(m, 1, 64));
    m = fmaxf(m, __shfl_xor(m, 2, 64));
    m = fmaxf(m, __shfl_xor(m, 4, 64));

    float s = __expf(a.x - m) + __expf(a.y - m) + __expf(a.z - m) + __expf(a.w - m)
            + __expf(b.x - m) + __expf(b.y - m) + __expf(b.z - m) + __expf(b.w - m)
            + __expf(c.x - m) + __expf(c.y - m) + __expf(c.z - m) + __expf(c.w - m)
            + __expf(d.x - m) + __expf(d.y - m) + __expf(d.z - m) + __expf(d.w - m);
    s += __shfl_xor(s, 1, 64);
    s += __shfl_xor(s, 2, 64);
    s += __shfl_xor(s, 4, 64);

    if (j == 0) {
      float loss = fmaxf(__logf(s) + m - xt, 0.0f);
      losses[row] = loss;
      atomicAdd(&lh[__float_as_uint(loss) >> 20], 1u);
    }
  }
  __syncthreads();
  unsigned* h = hist1 + (size_t)(blockIdx.x & (NREP - 1)) * 4096;
  for (int i = threadIdx.x; i < 4096; i += TPB) {
    unsigned v = lh[i];
    if (v) atomicAdd(&h[i], v);
  }
}

// ---- node 3: scan level 1 (single block, 64 threads) ----
__global__ void scan1_kernel(const unsigned* __restrict__ hist1,
                             Scalars* __restrict__ sc, int K) {
  int bin; unsigned above;
  scan_desc(hist1, 4096, NREP, (unsigned)K, &bin, &above);
  if (threadIdx.x == 0) {
    sc->sel1 = (unsigned)bin;
    sc->cnt_above = above;
    sc->krem = K - (int)above;
  }
}

// ---- node 4: 20-bit refine + hierarchical sums (no fence, no ticket) ----
__global__ __launch_bounds__(TPB) void refine_kernel(
    const float* __restrict__ losses, unsigned* __restrict__ hist2,
    float* __restrict__ hsum2, unsigned* __restrict__ fine,
    const Scalars* __restrict__ sc, double* __restrict__ partials, int N) {
  __shared__ unsigned lc[1024];
  __shared__ float lsum[1024];
  __shared__ double dsm[TPB / 64];
  for (int i = threadIdx.x; i < 1024; i += TPB) { lc[i] = 0; lsum[i] = 0.0f; }
  __syncthreads();

  const int lane = threadIdx.x & 63;
  const unsigned sel1 = sc->sel1;
  const float4* L4 = (const float4*)losses;
  const int n4 = N >> 2;
  double accS1 = 0.0;   // sum of elements in coarse bins strictly above sel1
  for (int idx = blockIdx.x * TPB + threadIdx.x; idx < n4;
       idx += REF_GRID * TPB) {
    float4 v = L4[idx];
#pragma unroll
    for (int comp = 0; comp < 4; ++comp) {
      float f = (comp == 0) ? v.x : (comp == 1) ? v.y : (comp == 2) ? v.z : v.w;
      unsigned b = __float_as_uint(f);
      unsigned hi = b >> 20;
      if (hi > sel1) {
        accS1 += (double)f;
      } else if (hi == sel1) {
        atomicAdd(&lc[(b >> 10) & 1023u], 1u);
        atomicAdd(&lsum[(b >> 10) & 1023u], f);
        atomicAdd(&fine[b & 0xFFFFFu], 1u);
      }
    }
  }
  accS1 = xor_reduce_d(accS1);
  if (lane == 0) dsm[threadIdx.x >> 6] = accS1;
  __syncthreads();
  if (threadIdx.x == 0)
    partials[blockIdx.x] = dsm[0] + dsm[1] + dsm[2] + dsm[3];

  unsigned* h = hist2 + (size_t)(blockIdx.x & (NREP - 1)) * 1024;
  for (int i = threadIdx.x; i < 1024; i += TPB) {
    unsigned c = lc[i];
    if (c) { atomicAdd(&h[i], c); atomicAdd(&hsum2[i], lsum[i]); }
  }
}

// ---- node 5: finalize (single block, 256 threads) ----
__global__ __launch_bounds__(TPB) void final_kernel(
    const unsigned* __restrict__ hist2, const float* __restrict__ hsum2,
    const unsigned* __restrict__ fine, const Scalars* __restrict__ sc,
    const double* __restrict__ partials, float* __restrict__ out, int K) {
  __shared__ double dsm[TPB / 64];
  __shared__ double S1sh;
  const int lane = threadIdx.x & 63;

  // S1 total: one partial per thread (REF_GRID == TPB)
  double s1 = partials[threadIdx.x];
  s1 = xor_reduce_d(s1);
  if (lane == 0) dsm[threadIdx.x >> 6] = s1;
  __syncthreads();
  if (threadIdx.x == 0) S1sh = dsm[0] + dsm[1] + dsm[2] + dsm[3];
  __syncthreads();

  if (threadIdx.x < 64) {
    const unsigned sel1 = sc->sel1;
    const unsigned krem = (unsigned)sc->krem;
    int sel2; unsigned above2;
    scan_desc(hist2, 1024, NREP, krem, &sel2, &above2);
    const unsigned krem2 = krem - above2;

    // S2: sums of 10-bit bins strictly above sel2 (within sel1 bin)
    double s2 = 0.0;
    for (int b = sel2 + 1 + lane; b < 1024; b += 64) s2 += (double)hsum2[b];
    s2 = xor_reduce_d(s2);

    // scan level 3 on fine counts within sel2's region
    const unsigned* freg = fine + ((size_t)sel2 << 10);
    int bin3; unsigned above3;
    scan_desc(freg, 1024, 1, krem2, &bin3, &above3);

    // S3: exact — all elements in a fine bin share the same 32-bit value
    const unsigned pfx = (sel1 << 20) | ((unsigned)sel2 << 10);
    double s3 = 0.0;
    for (int t = bin3 + 1 + lane; t < 1024; t += 64) {
      unsigned c = freg[t];
      if (c) s3 += (double)c * (double)__uint_as_float(pfx | (unsigned)t);
    }
    s3 = xor_reduce_d(s3);

    if (lane == 0) {
      unsigned thr_bits = pfx | (unsigned)bin3;
      unsigned cnt_gt = sc->cnt_above + above2 + above3;
      double thrv = (double)__uint_as_float(thr_bits);
      double mean = (S1sh + s2 + s3 +
                     (double)(K - (int)cnt_gt) * thrv) / (double)K;
      *out = (float)mean;
    }
  }
}

extern "C" void kernel_launch(void* const* d_in, const int* in_sizes, int n_in,
                              void* d_out, int out_size, void* d_ws, size_t ws_size,
                              hipStream_t stream) {
  const float* x = (const float*)d_in[0];
  const int* tgt = (const int*)d_in[1];
  float* out = (float*)d_out;
  int N = in_sizes[1];                 // 262144 rows
  int K = (int)(0.7 * (double)N);      // 183500, matches Python int()

  char* ws = (char*)d_ws;
  const size_t OFF_H1 = (size_t)N * 4;                       // losses: 1 MiB
  const size_t OFF_H2 = OFF_H1 + (size_t)NREP * 4096 * 4;    // hist1: 128 KiB
  const size_t OFF_HS = OFF_H2 + (size_t)NREP * 1024 * 4;    // hist2: 32 KiB
  const size_t OFF_SC = OFF_HS + 1024 * 4;                   // hsum2: 4 KiB
  const size_t OFF_FN = OFF_SC + 128;                        // scalars
  const size_t OFF_PT = OFF_FN + (size_t)(1u << 20) * 4;     // fine: 4 MiB
  // partials: REF_GRID doubles after OFF_PT (written before read; no zeroing)

  float* losses = (float*)ws;
  unsigned* hist1 = (unsigned*)(ws + OFF_H1);
  unsigned* hist2 = (unsigned*)(ws + OFF_H2);
  float* hsum2 = (float*)(ws + OFF_HS);
  Scalars* sc = (Scalars*)(ws + OFF_SC);
  unsigned* fine = (unsigned*)(ws + OFF_FN);
  double* partials = (double*)(ws + OFF_PT);

  // zero hist1 + hist2 + hsum2 + scalars + fine in one fill (~4.4 MB)
  hipMemsetAsync(ws + OFF_H1, 0, OFF_PT - OFF_H1, stream);

  loss_hist_kernel<<<LOSS_GRID, TPB, 0, stream>>>(x, tgt, losses, hist1, N);
  scan1_kernel<<<1, 64, 0, stream>>>(hist1, sc, K);
  refine_kernel<<<REF_GRID, TPB, 0, stream>>>(losses, hist2, hsum2, fine, sc,
                                              partials, N);
  final_kernel<<<1, TPB, 0, stream>>>(hist2, hsum2, fine, sc, partials, out, K);
}

// Round 8
// 211.489 us; speedup vs baseline: 2.6413x; 1.0123x over previous
//
#include <hip/hip_runtime.h>

// topk cross-entropy: N=262144 rows, C=128 classes, K = int(0.7*N) = 183500.
// Round 8: loss kernel restructured for ILP — 16 rows/wave, NO loop (8
// back-to-back float4 loads/lane, 2-level shuffles), exact 4096-block grid.
// scan1 folded into refine (per-block redundant self-scan; block 0 publishes).
// 4 nodes: memset -> loss+hist12 -> refine(+scan1)+sums -> finalize(1 blk).
// NO device-scope fences (R4/R5/R6: ~us/block cost on CDNA4).
// Exact 12/10/10-bit radix select on float bits (losses >= 0 => monotone);
// tie-exact mean = (S1 + S2 + S3 + (K - cnt_gt)*thr) / K.

#define NCLASS 128
#define NREP 8
#define TPB 256
#define REF_GRID 256

struct Scalars {
  unsigned sel1;
  unsigned cnt_above;   // count strictly above sel1 bin (after pass 1)
  int krem;             // remaining rank within sel1 bin
};

__device__ __forceinline__ unsigned suffix_incl_u(unsigned x, int lane) {
#pragma unroll
  for (int off = 1; off < 64; off <<= 1) {
    unsigned v = __shfl_down(x, off, 64);
    if (lane + off < 64) x += v;
  }
  return x;
}

__device__ __forceinline__ double xor_reduce_d(double x) {
#pragma unroll
  for (int off = 32; off > 0; off >>= 1) x += __shfl_xor(x, off, 64);
  return x;
}

// Descending-rank select on a histogram (nrep replicas summed). Must be called
// by threads 0..63 of one wave. Outputs valid on all 64 lanes.
__device__ __forceinline__ void scan_desc(const unsigned* __restrict__ hist,
                                          int nbins, int nrep, unsigned Ktar,
                                          int* bin_out, unsigned* above_out) {
  const int lane = threadIdx.x;
  const int bpt = nbins >> 6;
  unsigned csum = 0;
  for (int rr = 0; rr < nrep; ++rr) {
    const unsigned* hp = hist + (size_t)rr * nbins + lane * bpt;
    for (int i = 0; i < bpt; ++i) csum += hp[i];
  }
  unsigned suf = suffix_incl_u(csum, lane);
  unsigned long long mask = __ballot(suf >= Ktar);
  int c = 63 - __builtin_clzll(mask);
  unsigned aboveC = __shfl(suf - csum, c, 64);   // strictly above chunk c

  unsigned h = 0;
  if (lane < bpt)
    for (int rr = 0; rr < nrep; ++rr)
      h += hist[(size_t)rr * nbins + c * bpt + lane];
  unsigned suf2 = suffix_incl_u(h, lane);
  unsigned long long mask2 = __ballot((lane < bpt) && (aboveC + suf2 >= Ktar));
  int u = 63 - __builtin_clzll(mask2);
  unsigned above = aboveC + __shfl(suf2 - h, u, 64); // strictly above bin
  *bin_out = c * bpt + u;
  *above_out = above;
}

// ---- node 2: losses + 12-bit histogram. 16 rows/wave, no loop:
//      lane quad (j=lane&3) covers one full 64B line per load instruction;
//      8 loads/lane = 32 elems; 2-level shuffle reductions. ----
__global__ __launch_bounds__(TPB) void loss_hist_kernel(
    const float* __restrict__ x, const int* __restrict__ tgt,
    float* __restrict__ losses, unsigned* __restrict__ hist1, int N) {
  __shared__ unsigned lh[4096];
  for (int i = threadIdx.x; i < 4096; i += TPB) lh[i] = 0;
  __syncthreads();

  const int lane = threadIdx.x & 63;
  const int j = lane & 3;        // float4 column group within row
  const int r = lane >> 2;       // row within the wave's 16-row group
  const int wave = blockIdx.x * (TPB / 64) + (threadIdx.x >> 6);
  const int row = wave * 16 + r; // grid exactly covers N

  const float4* rp = (const float4*)(x + (size_t)row * NCLASS);
  float4 v0 = rp[j];
  float4 v1 = rp[j + 4];
  float4 v2 = rp[j + 8];
  float4 v3 = rp[j + 12];
  float4 v4 = rp[j + 16];
  float4 v5 = rp[j + 20];
  float4 v6 = rp[j + 24];
  float4 v7 = rp[j + 28];
  float xt = 0.0f;
  if (j == 0) {                  // 16 lanes gather the target logit
    int t = tgt[row];
    xt = x[(size_t)row * NCLASS + t];
  }

  float m = fmaxf(fmaxf(fmaxf(v0.x, v0.y), fmaxf(v0.z, v0.w)),
                  fmaxf(fmaxf(v1.x, v1.y), fmaxf(v1.z, v1.w)));
  m = fmaxf(m, fmaxf(fmaxf(fmaxf(v2.x, v2.y), fmaxf(v2.z, v2.w)),
                     fmaxf(fmaxf(v3.x, v3.y), fmaxf(v3.z, v3.w))));
  m = fmaxf(m, fmaxf(fmaxf(fmaxf(v4.x, v4.y), fmaxf(v4.z, v4.w)),
                     fmaxf(fmaxf(v5.x, v5.y), fmaxf(v5.z, v5.w))));
  m = fmaxf(m, fmaxf(fmaxf(fmaxf(v6.x, v6.y), fmaxf(v6.z, v6.w)),
                     fmaxf(fmaxf(v7.x, v7.y), fmaxf(v7.z, v7.w))));
  m = fmaxf(m, __shfl_xor(m, 1, 64));
  m = fmaxf(m, __shfl_xor(m, 2, 64));

  float s = __expf(v0.x - m) + __expf(v0.y - m) + __expf(v0.z - m) + __expf(v0.w - m)
          + __expf(v1.x - m) + __expf(v1.y - m) + __expf(v1.z - m) + __expf(v1.w - m)
          + __expf(v2.x - m) + __expf(v2.y - m) + __expf(v2.z - m) + __expf(v2.w - m)
          + __expf(v3.x - m) + __expf(v3.y - m) + __expf(v3.z - m) + __expf(v3.w - m)
          + __expf(v4.x - m) + __expf(v4.y - m) + __expf(v4.z - m) + __expf(v4.w - m)
          + __expf(v5.x - m) + __expf(v5.y - m) + __expf(v5.z - m) + __expf(v5.w - m)
          + __expf(v6.x - m) + __expf(v6.y - m) + __expf(v6.z - m) + __expf(v6.w - m)
          + __expf(v7.x - m) + __expf(v7.y - m) + __expf(v7.z - m) + __expf(v7.w - m);
  s += __shfl_xor(s, 1, 64);
  s += __shfl_xor(s, 2, 64);

  if (j == 0) {
    float loss = fmaxf(__logf(s) + m - xt, 0.0f);
    losses[row] = loss;
    atomicAdd(&lh[__float_as_uint(loss) >> 20], 1u);
  }
  __syncthreads();
  unsigned* h = hist1 + (size_t)(blockIdx.x & (NREP - 1)) * 4096;
  for (int i = threadIdx.x; i < 4096; i += TPB) {
    unsigned v = lh[i];
    if (v) atomicAdd(&h[i], v);
  }
}

// ---- node 3: self-scan1 + 20-bit refine + hierarchical sums ----
__global__ __launch_bounds__(TPB) void refine_kernel(
    const float* __restrict__ losses, const unsigned* __restrict__ hist1,
    unsigned* __restrict__ hist2, float* __restrict__ hsum2,
    unsigned* __restrict__ fine, Scalars* __restrict__ sc,
    double* __restrict__ partials, int N, int K) {
  __shared__ unsigned lc[1024];
  __shared__ float lsum[1024];
  __shared__ double dsm[TPB / 64];
  __shared__ unsigned sel1_sh;
  for (int i = threadIdx.x; i < 1024; i += TPB) { lc[i] = 0; lsum[i] = 0.0f; }

  // redundant per-block scan1 (reads 128 KiB of L2-hot hist1)
  if (threadIdx.x < 64) {
    int bin; unsigned above;
    scan_desc(hist1, 4096, NREP, (unsigned)K, &bin, &above);
    if (threadIdx.x == 0) {
      sel1_sh = (unsigned)bin;
      if (blockIdx.x == 0) {       // publish for final_kernel
        sc->sel1 = (unsigned)bin;
        sc->cnt_above = above;
        sc->krem = K - (int)above;
      }
    }
  }
  __syncthreads();

  const int lane = threadIdx.x & 63;
  const unsigned sel1 = sel1_sh;
  const float4* L4 = (const float4*)losses;
  const int n4 = N >> 2;
  double accS1 = 0.0;   // sum of elements in coarse bins strictly above sel1
  for (int idx = blockIdx.x * TPB + threadIdx.x; idx < n4;
       idx += REF_GRID * TPB) {
    float4 v = L4[idx];
#pragma unroll
    for (int comp = 0; comp < 4; ++comp) {
      float f = (comp == 0) ? v.x : (comp == 1) ? v.y : (comp == 2) ? v.z : v.w;
      unsigned b = __float_as_uint(f);
      unsigned hi = b >> 20;
      if (hi > sel1) {
        accS1 += (double)f;
      } else if (hi == sel1) {
        atomicAdd(&lc[(b >> 10) & 1023u], 1u);
        atomicAdd(&lsum[(b >> 10) & 1023u], f);
        atomicAdd(&fine[b & 0xFFFFFu], 1u);
      }
    }
  }
  accS1 = xor_reduce_d(accS1);
  if (lane == 0) dsm[threadIdx.x >> 6] = accS1;
  __syncthreads();
  if (threadIdx.x == 0)
    partials[blockIdx.x] = dsm[0] + dsm[1] + dsm[2] + dsm[3];

  unsigned* h = hist2 + (size_t)(blockIdx.x & (NREP - 1)) * 1024;
  for (int i = threadIdx.x; i < 1024; i += TPB) {
    unsigned c = lc[i];
    if (c) { atomicAdd(&h[i], c); atomicAdd(&hsum2[i], lsum[i]); }
  }
}

// ---- node 4: finalize (single block, 256 threads) ----
__global__ __launch_bounds__(TPB) void final_kernel(
    const unsigned* __restrict__ hist2, const float* __restrict__ hsum2,
    const unsigned* __restrict__ fine, const Scalars* __restrict__ sc,
    const double* __restrict__ partials, float* __restrict__ out, int K) {
  __shared__ double dsm[TPB / 64];
  __shared__ double S1sh;
  const int lane = threadIdx.x & 63;

  // S1 total: one partial per thread (REF_GRID == TPB)
  double s1 = partials[threadIdx.x];
  s1 = xor_reduce_d(s1);
  if (lane == 0) dsm[threadIdx.x >> 6] = s1;
  __syncthreads();
  if (threadIdx.x == 0) S1sh = dsm[0] + dsm[1] + dsm[2] + dsm[3];
  __syncthreads();

  if (threadIdx.x < 64) {
    const unsigned sel1 = sc->sel1;
    const unsigned krem = (unsigned)sc->krem;
    int sel2; unsigned above2;
    scan_desc(hist2, 1024, NREP, krem, &sel2, &above2);
    const unsigned krem2 = krem - above2;

    // S2: sums of 10-bit bins strictly above sel2 (within sel1 bin)
    double s2 = 0.0;
    for (int b = sel2 + 1 + lane; b < 1024; b += 64) s2 += (double)hsum2[b];
    s2 = xor_reduce_d(s2);

    // scan level 3 on fine counts within sel2's region
    const unsigned* freg = fine + ((size_t)sel2 << 10);
    int bin3; unsigned above3;
    scan_desc(freg, 1024, 1, krem2, &bin3, &above3);

    // S3: exact — all elements in a fine bin share the same 32-bit value
    const unsigned pfx = (sel1 << 20) | ((unsigned)sel2 << 10);
    double s3 = 0.0;
    for (int t = bin3 + 1 + lane; t < 1024; t += 64) {
      unsigned c = freg[t];
      if (c) s3 += (double)c * (double)__uint_as_float(pfx | (unsigned)t);
    }
    s3 = xor_reduce_d(s3);

    if (lane == 0) {
      unsigned thr_bits = pfx | (unsigned)bin3;
      unsigned cnt_gt = sc->cnt_above + above2 + above3;
      double thrv = (double)__uint_as_float(thr_bits);
      double mean = (S1sh + s2 + s3 +
                     (double)(K - (int)cnt_gt) * thrv) / (double)K;
      *out = (float)mean;
    }
  }
}

extern "C" void kernel_launch(void* const* d_in, const int* in_sizes, int n_in,
                              void* d_out, int out_size, void* d_ws, size_t ws_size,
                              hipStream_t stream) {
  const float* x = (const float*)d_in[0];
  const int* tgt = (const int*)d_in[1];
  float* out = (float*)d_out;
  int N = in_sizes[1];                 // 262144 rows
  int K = (int)(0.7 * (double)N);      // 183500, matches Python int()

  char* ws = (char*)d_ws;
  const size_t OFF_H1 = (size_t)N * 4;                       // losses: 1 MiB
  const size_t OFF_H2 = OFF_H1 + (size_t)NREP * 4096 * 4;    // hist1: 128 KiB
  const size_t OFF_HS = OFF_H2 + (size_t)NREP * 1024 * 4;    // hist2: 32 KiB
  const size_t OFF_SC = OFF_HS + 1024 * 4;                   // hsum2: 4 KiB
  const size_t OFF_FN = OFF_SC + 128;                        // scalars
  const size_t OFF_PT = OFF_FN + (size_t)(1u << 20) * 4;     // fine: 4 MiB
  // partials: REF_GRID doubles after OFF_PT (written before read; no zeroing)

  float* losses = (float*)ws;
  unsigned* hist1 = (unsigned*)(ws + OFF_H1);
  unsigned* hist2 = (unsigned*)(ws + OFF_H2);
  float* hsum2 = (float*)(ws + OFF_HS);
  Scalars* sc = (Scalars*)(ws + OFF_SC);
  unsigned* fine = (unsigned*)(ws + OFF_FN);
  double* partials = (double*)(ws + OFF_PT);

  // zero hist1 + hist2 + hsum2 + scalars + fine in one fill (~4.4 MB)
  hipMemsetAsync(ws + OFF_H1, 0, OFF_PT - OFF_H1, stream);

  loss_hist_kernel<<<N / 64, TPB, 0, stream>>>(x, tgt, losses, hist1, N);
  refine_kernel<<<REF_GRID, TPB, 0, stream>>>(losses, hist1, hist2, hsum2,
                                              fine, sc, partials, N, K);
  final_kernel<<<1, TPB, 0, stream>>>(hist2, hsum2, fine, sc, partials, out, K);
}